// Round 3
// baseline (148.655 us; speedup 1.0000x reference)
//
#include <hip/hip_runtime.h>
#include <math.h>

#define BATCH  2
#define NVOX   8000
#define MT     32            // queries per attn block
#define KT     64            // keys per tile
#define NTILES 125
#define QTILES 250
#define LOG2E  1.44269504f
#define MSTAT  32.0f         // static softmax shift (log2 domain)

typedef float  f32x16 __attribute__((ext_vector_type(16)));
typedef __bf16 bf16x8 __attribute__((ext_vector_type(8)));
typedef unsigned short u16x8 __attribute__((ext_vector_type(8)));

__device__ __forceinline__ unsigned short f2bf(float f) {
    return __builtin_bit_cast(unsigned short, (__bf16)f);
}
// HW packed f32x2 -> bf16x2 (one VOP3 instead of ~8 VALU of software RNE)
__device__ __forceinline__ unsigned int packbf(float lo, float hi) {
    unsigned int r;
    asm("v_cvt_pk_bf16_f32 %0, %1, %2" : "=v"(r) : "v"(lo), "v"(hi));
    return r;
}
// schedulable native 2^x (no opaque asm block -> compiler can interleave)
__device__ __forceinline__ float fexp2(float x) {
    return __builtin_amdgcn_exp2f(x);
}
// v_permlane32_swap_b32: a' = {a.lo, b.lo}, b' = {a.hi, b.hi}
__device__ __forceinline__ void plswap(unsigned &a, unsigned &b) {
    asm("v_permlane32_swap_b32 %0, %1" : "+v"(a), "+v"(b));
}

// V workspace layout (R8/R9, proven): fragment-linear
//   u16 index = (b*125+T)*4096 + s2*1024 + cg*512 + p*256 + c31*8 + j
//   holds V[c=cg*32+c31][key = T*64 + s2*16 + p*8 + j]

// ---------------------------------------------------------------------------
// Kernel 1: projection GEMM. 500 blocks x 192 thr, 32 distinct voxels/block.
// (R9 verbatim — proven; qkv is off the critical path.)
// ---------------------------------------------------------------------------
__global__ __launch_bounds__(192) void qkv_kernel(
    const float* __restrict__ x,
    const float* __restrict__ wq, const float* __restrict__ bq,
    const float* __restrict__ wk, const float* __restrict__ bk,
    const float* __restrict__ wv, const float* __restrict__ bv,
    unsigned short* __restrict__ qws, unsigned short* __restrict__ kws,
    unsigned short* __restrict__ vws)
{
    // st rows: 0-7 q-hi, 8-15 k, 16-79 v, 80-87 q-lo; cols = 32 voxels; stride 40
    __shared__ __align__(16) unsigned short st[88 * 40];
    const int t = threadIdx.x, lane = t & 63, ot = t >> 6;   // ot 0..2
    const int l31 = lane & 31, h = lane >> 5;
    const int blk = blockIdx.x, b = blk / 250, v0 = (blk % 250) * 32;
    const int n = v0 + l31;

    const int o = ot * 32 + l31;
    const float* wsrc;
    float scale = 1.0f;
    if (o < 8)       { wsrc = wq + o * 64; scale = LOG2E; }
    else if (o < 16) { wsrc = wk + (o - 8) * 64; }
    else             { wsrc = wv + ((o - 16) & 63) * 64; }   // o>=80: junk, never stored

    bf16x8 Ah[4], Al[4];
#pragma unroll
    for (int cc = 0; cc < 4; ++cc) {
        float4 w0 = *(const float4*)(wsrc + cc * 16 + 8 * h);
        float4 w1 = *(const float4*)(wsrc + cc * 16 + 8 * h + 4);
        float wf[8] = { w0.x, w0.y, w0.z, w0.w, w1.x, w1.y, w1.z, w1.w };
        unsigned short hh[8], ll[8];
#pragma unroll
        for (int j = 0; j < 8; ++j) {
            float wv_ = wf[j] * scale;
            __bf16 hb = (__bf16)wv_;
            hh[j] = __builtin_bit_cast(unsigned short, hb);
            ll[j] = f2bf(wv_ - (float)hb);
        }
        Ah[cc] = __builtin_bit_cast(bf16x8, *(u16x8*)hh);
        Al[cc] = __builtin_bit_cast(bf16x8, *(u16x8*)ll);
    }

    bf16x8 Bhi[4], Blo[4];
    const float* xb = x + (size_t)b * 64 * NVOX + n;
#pragma unroll
    for (int cc = 0; cc < 4; ++cc) {
        unsigned short bh[8], bl[8];
#pragma unroll
        for (int j = 0; j < 8; ++j) {
            float xf = xb[(size_t)(cc * 16 + 8 * h + j) * NVOX];
            __bf16 xh = (__bf16)xf;
            bh[j] = __builtin_bit_cast(unsigned short, xh);
            bl[j] = f2bf(xf - (float)xh);
        }
        Bhi[cc] = __builtin_bit_cast(bf16x8, *(u16x8*)bh);
        Blo[cc] = __builtin_bit_cast(bf16x8, *(u16x8*)bl);
    }

    f32x16 acc;
#pragma unroll
    for (int r = 0; r < 16; ++r) acc[r] = 0.0f;
#pragma unroll
    for (int cc = 0; cc < 4; ++cc) {
        acc = __builtin_amdgcn_mfma_f32_32x32x16_bf16(Ah[cc], Bhi[cc], acc, 0, 0, 0);
        acc = __builtin_amdgcn_mfma_f32_32x32x16_bf16(Al[cc], Bhi[cc], acc, 0, 0, 0);
        acc = __builtin_amdgcn_mfma_f32_32x32x16_bf16(Ah[cc], Blo[cc], acc, 0, 0, 0);
    }

#pragma unroll
    for (int r = 0; r < 16; ++r) {
        int oo = ot * 32 + (r & 3) + 8 * (r >> 2) + 4 * h;
        if (oo >= 80) continue;
        float bias = (oo < 8) ? bq[oo] * LOG2E : (oo < 16) ? bk[oo - 8] : bv[oo - 16];
        float v = acc[r] + bias;
        if (oo < 8) {
            __bf16 hb = (__bf16)v;
            st[oo * 40 + l31]        = __builtin_bit_cast(unsigned short, hb);
            st[(80 + oo) * 40 + l31] = f2bf(v - (float)hb);
        } else {
            st[oo * 40 + l31] = f2bf(v);
        }
    }
    __syncthreads();

    // ---- coalesced 16B stores ----
    for (int idx = t; idx < 256; idx += 192) {
        int ch = idx >> 2, q = idx & 3;
        int T = v0 >> 6;
        int off = (v0 & 63) + q * 8;
        int s2 = off >> 4, p = (off >> 3) & 1;
        int cg = ch >> 5, c31 = ch & 31;
        size_t dst = (size_t)(b * 125 + T) * 4096 + s2 * 1024 + cg * 512
                   + p * 256 + c31 * 8;
        *(uint4*)(vws + dst) = *(const uint4*)&st[(16 + ch) * 40 + q * 8];
    }
    if (t >= 128) {                      // qws: 32 vox x {hi,lo} = 64 units
        int i = t - 128, vox = i >> 1, half = i & 1;
        int rbase = half ? 80 : 0;
        unsigned short g[8];
#pragma unroll
        for (int r = 0; r < 8; ++r) g[r] = st[(rbase + r) * 40 + vox];
        *(uint4*)(qws + (size_t)(b * NVOX + v0 + vox) * 16 + half * 8) = *(uint4*)g;
    } else if (t >= 96) {                // kws: 32 vox
        int vox = t - 96;
        unsigned short g[8];
#pragma unroll
        for (int r = 0; r < 8; ++r) g[r] = st[(8 + r) * 40 + vox];
        *(uint4*)(kws + (size_t)(b * NVOX + v0 + vox) * 8) = *(uint4*)g;
    }
}

// ---------------------------------------------------------------------------
// Kernel 2: flash attention. 500 blocks x 512 thr, wave w owns tiles T = w+8S,
// pipelined by one tile. R15 deltas (occupancy push: total regs <= 128 so TWO
// blocks co-reside per CU -> 4 waves/SIMD instead of 2):
//   (a) E-split: E0 fully processed (exp/pack/swap) before E1's MFMA issues
//       -> peak E transient 32 -> 16 regs
//   (b) K double-buffer dropped: next-iter K loads go directly into kf0c/kf1c
//       after E1 consumed them (lead ~ most of an iter >> L2 latency) -> -8 regs
//   (c) havePrev bool -> (S > 0): valid tiles are a prefix in S per wave
//   (d) __launch_bounds__(512, 4): 4 waves/SIMD target = 2 blocks/CU
// (R16: resubmit of R15 verbatim — bench container failed, no data produced.)
// ---------------------------------------------------------------------------
__global__ __launch_bounds__(512, 4) void attn_kernel(
    const unsigned short* __restrict__ qws, const unsigned short* __restrict__ kws,
    const unsigned short* __restrict__ vws, const float* __restrict__ x,
    const float* __restrict__ gamma, float* __restrict__ out)
{
    __shared__ float smem_f[8704];          // 32KB merge + 2KB l
    float* l_sh = smem_f + 8192;            // [8][64]

    const int blk = blockIdx.x, b = blk / QTILES, m0 = (blk % QTILES) * MT;
    const int t = threadIdx.x, lane = t & 63, w = t >> 6;
    const int l31 = lane & 31, h = lane >> 5;

    // Q B-frag (log2e pre-folded): col=query l31, h=0 hi / h=1 lo
    const bf16x8 qf = __builtin_bit_cast(bf16x8,
        *(const u16x8*)(qws + (size_t)(b * NVOX + m0 + l31) * 16 + h * 8));

    const unsigned short* ksrc = kws + (size_t)b * NVOX * 8;
    const unsigned short* vbase = vws + (size_t)b * 512000 + h * 256 + l31 * 8;

    f32x16 acc0, acc1, mC;
#pragma unroll
    for (int r = 0; r < 16; ++r) { acc0[r] = 0.0f; acc1[r] = 0.0f; mC[r] = -MSTAT; }
    float sA = 0.0f, sB = 0.0f, sC = 0.0f, sD = 0.0f;

    uint4 va0[4], va1[4];
    uint4 pf[4];
    bf16x8 kf0c = __builtin_bit_cast(bf16x8, *(const u16x8*)(ksrc + (size_t)(w * KT + l31) * 8));
    bf16x8 kf1c = __builtin_bit_cast(bf16x8, *(const u16x8*)(ksrc + (size_t)(w * KT + 32 + l31) * 8));

#pragma unroll 1
    for (int S = 0; S < 16; ++S) {
        const int T = w + 8 * S;
        if (T < NTILES) {
            // 1. E0 = K0·Q - MSTAT (shift folded into accumulator init)
            f32x16 E0 = __builtin_amdgcn_mfma_f32_32x32x16_bf16(kf0c, qf, mC, 0, 0, 0);

            // 2. PV of previous tile (independent of E0 — fills MFMA pipe
            //    while E0's result is in flight). pf/va die here.
            if (S > 0) {
                __builtin_amdgcn_s_setprio(1);
#pragma unroll
                for (int s2 = 0; s2 < 4; ++s2)
                    acc0 = __builtin_amdgcn_mfma_f32_32x32x16_bf16(
                        __builtin_bit_cast(bf16x8, va0[s2]),
                        __builtin_bit_cast(bf16x8, pf[s2]), acc0, 0, 0, 0);
#pragma unroll
                for (int s2 = 0; s2 < 4; ++s2)
                    acc1 = __builtin_amdgcn_mfma_f32_32x32x16_bf16(
                        __builtin_bit_cast(bf16x8, va1[s2]),
                        __builtin_bit_cast(bf16x8, pf[s2]), acc1, 0, 0, 0);
                __builtin_amdgcn_s_setprio(0);
            }

            // 3. V tile for THIS T (consumed next iteration) — reuses the va
            //    regs freed by step 2; lands under the exp chains below.
            {
                const unsigned short* vt = vbase + (size_t)T * 4096;
#pragma unroll
                for (int s2 = 0; s2 < 4; ++s2) {
                    va0[s2] = *(const uint4*)(vt + s2 * 1024);
                    va1[s2] = *(const uint4*)(vt + s2 * 1024 + 512);
                }
            }

            // 4. process E0 -> pf[0], pf[1]  (E0 dies; peak E regs stay at 16)
            {
                unsigned int pk0[8];
#pragma unroll
                for (int g = 0; g < 8; ++g) {
                    float pa = fexp2(E0[2 * g]);
                    float pb = fexp2(E0[2 * g + 1]);
                    sA += pa; sB += pb;
                    pk0[g] = packbf(pa, pb);
                }
                unsigned a0, b0;
                a0 = pk0[0]; b0 = pk0[2]; plswap(a0, b0); pf[0].x = a0; pf[0].z = b0;
                a0 = pk0[1]; b0 = pk0[3]; plswap(a0, b0); pf[0].y = a0; pf[0].w = b0;
                a0 = pk0[4]; b0 = pk0[6]; plswap(a0, b0); pf[1].x = a0; pf[1].z = b0;
                a0 = pk0[5]; b0 = pk0[7]; plswap(a0, b0); pf[1].y = a0; pf[1].w = b0;
            }

            // 5. E1 = K1·Q - MSTAT (issued only now: its output reuses E0's regs)
            f32x16 E1 = __builtin_amdgcn_mfma_f32_32x32x16_bf16(kf1c, qf, mC, 0, 0, 0);

            // 6. K loads for T+8 — straight into kf0c/kf1c (dead after step 5).
            if (T + 8 < NTILES) {
                const int nn = (T + 8) * KT;
                kf0c = __builtin_bit_cast(bf16x8, *(const u16x8*)(ksrc + (size_t)(nn + l31) * 8));
                kf1c = __builtin_bit_cast(bf16x8, *(const u16x8*)(ksrc + (size_t)(nn + 32 + l31) * 8));
            }

            // 7. process E1 -> pf[2], pf[3]
            {
                unsigned int pk1[8];
#pragma unroll
                for (int g = 0; g < 8; ++g) {
                    float pa = fexp2(E1[2 * g]);
                    float pb = fexp2(E1[2 * g + 1]);
                    sC += pa; sD += pb;
                    pk1[g] = packbf(pa, pb);
                }
                unsigned a0, b0;
                a0 = pk1[0]; b0 = pk1[2]; plswap(a0, b0); pf[2].x = a0; pf[2].z = b0;
                a0 = pk1[1]; b0 = pk1[3]; plswap(a0, b0); pf[2].y = a0; pf[2].w = b0;
                a0 = pk1[4]; b0 = pk1[6]; plswap(a0, b0); pf[3].x = a0; pf[3].z = b0;
                a0 = pk1[5]; b0 = pk1[7]; plswap(a0, b0); pf[3].y = a0; pf[3].w = b0;
            }
        }
    }

    // ---- drain: PV for the last tile
    __builtin_amdgcn_s_setprio(1);
#pragma unroll
    for (int s2 = 0; s2 < 4; ++s2)
        acc0 = __builtin_amdgcn_mfma_f32_32x32x16_bf16(
            __builtin_bit_cast(bf16x8, va0[s2]),
            __builtin_bit_cast(bf16x8, pf[s2]), acc0, 0, 0, 0);
#pragma unroll
    for (int s2 = 0; s2 < 4; ++s2)
        acc1 = __builtin_amdgcn_mfma_f32_32x32x16_bf16(
            __builtin_bit_cast(bf16x8, va1[s2]),
            __builtin_bit_cast(bf16x8, pf[s2]), acc1, 0, 0, 0);
    __builtin_amdgcn_s_setprio(0);

    // ---- tree merge (plain sums, static m) ----
    l_sh[w * 64 + lane] = (sA + sB) + (sC + sD);
    float* mw = smem_f;
    auto wr = [&](int srcw) {
#pragma unroll
        for (int r4 = 0; r4 < 4; ++r4) {
            *(float4*)&mw[((size_t)(srcw * 2 + 0) * 64 + lane) * 16 + 4 * r4] =
                make_float4(acc0[4*r4], acc0[4*r4+1], acc0[4*r4+2], acc0[4*r4+3]);
            *(float4*)&mw[((size_t)(srcw * 2 + 1) * 64 + lane) * 16 + 4 * r4] =
                make_float4(acc1[4*r4], acc1[4*r4+1], acc1[4*r4+2], acc1[4*r4+3]);
        }
    };
    auto rd = [&](int srcw) {
#pragma unroll
        for (int r4 = 0; r4 < 4; ++r4) {
            float4 a = *(const float4*)&mw[((size_t)(srcw * 2 + 0) * 64 + lane) * 16 + 4 * r4];
            float4 c = *(const float4*)&mw[((size_t)(srcw * 2 + 1) * 64 + lane) * 16 + 4 * r4];
            acc0[4*r4]   += a.x; acc0[4*r4+1] += a.y; acc0[4*r4+2] += a.z; acc0[4*r4+3] += a.w;
            acc1[4*r4]   += c.x; acc1[4*r4+1] += c.y; acc1[4*r4+2] += c.z; acc1[4*r4+3] += c.w;
        }
    };
    if (w >= 4) wr(w - 4);
    __syncthreads();
    if (w < 4) rd(w);
    __syncthreads();
    if (w >= 2 && w < 4) wr(w - 2);
    __syncthreads();
    if (w < 2) rd(w);
    __syncthreads();
    if (w == 1) wr(0);
    __syncthreads();
    if (w == 0) {
        rd(0);
        float l_tot = 0.0f;
#pragma unroll
        for (int ww = 0; ww < 8; ++ww)
            l_tot += l_sh[ww * 64 + l31] + l_sh[ww * 64 + 32 + l31];
        const float inv = 1.0f / l_tot;
        const float g = gamma[0];
#pragma unroll
        for (int r = 0; r < 16; ++r) {
            int c = (r & 3) + 8 * (r >> 2) + 4 * h;
            size_t i0 = ((size_t)b * 64 + c) * NVOX + m0 + l31;
            size_t i1 = ((size_t)b * 64 + c + 32) * NVOX + m0 + l31;
            out[i0] = g * (acc0[r] * inv) + x[i0];
            out[i1] = g * (acc1[r] * inv) + x[i1];
        }
    }
}

// ---------------------------------------------------------------------------
extern "C" void kernel_launch(void* const* d_in, const int* in_sizes, int n_in,
                              void* d_out, int out_size, void* d_ws, size_t ws_size,
                              hipStream_t stream) {
    const float* x     = (const float*)d_in[0];
    const float* wq    = (const float*)d_in[1];
    const float* bq    = (const float*)d_in[2];
    const float* wk    = (const float*)d_in[3];
    const float* bk    = (const float*)d_in[4];
    const float* wv    = (const float*)d_in[5];
    const float* bv    = (const float*)d_in[6];
    const float* gamma = (const float*)d_in[7];
    float* out = (float*)d_out;

    unsigned short* qws = (unsigned short*)d_ws;            // [16000][16] hi|lo (log2e-scaled)
    unsigned short* kws = qws + (size_t)BATCH * NVOX * 16;  // [16000][8]
    unsigned short* vws = kws + (size_t)BATCH * NVOX * 8;   // [2][125][4][2][2][32][8] frag-linear

    qkv_kernel<<<500, 192, 0, stream>>>(x, wq, bq, wk, bk, wv, bv, qws, kws, vws);
    attn_kernel<<<BATCH * QTILES, 512, 0, stream>>>(qws, kws, vws, x, gamma, out);
}

// Round 4
// 106.705 us; speedup vs baseline: 1.3931x; 1.3931x over previous
//
#include <hip/hip_runtime.h>
#include <math.h>

#define BATCH  2
#define NVOX   8000
#define MT     32            // queries per attn block
#define KT     64            // keys per tile
#define NTILES 125
#define QTILES 250
#define LOG2E  1.44269504f
#define MSTAT  32.0f         // static softmax shift (log2 domain)

typedef float  f32x16 __attribute__((ext_vector_type(16)));
typedef __bf16 bf16x8 __attribute__((ext_vector_type(8)));
typedef unsigned short u16x8 __attribute__((ext_vector_type(8)));

__device__ __forceinline__ unsigned short f2bf(float f) {
    return __builtin_bit_cast(unsigned short, (__bf16)f);
}
// HW packed f32x2 -> bf16x2 (one VOP3 instead of ~8 VALU of software RNE)
__device__ __forceinline__ unsigned int packbf(float lo, float hi) {
    unsigned int r;
    asm("v_cvt_pk_bf16_f32 %0, %1, %2" : "=v"(r) : "v"(lo), "v"(hi));
    return r;
}
// schedulable native 2^x (no opaque asm block -> compiler can interleave)
__device__ __forceinline__ float fexp2(float x) {
    return __builtin_amdgcn_exp2f(x);
}
// v_permlane32_swap_b32: a' = {a.lo, b.lo}, b' = {a.hi, b.hi}
__device__ __forceinline__ void plswap(unsigned &a, unsigned &b) {
    asm("v_permlane32_swap_b32 %0, %1" : "+v"(a), "+v"(b));
}

// V workspace layout (R8/R9, proven): fragment-linear
//   u16 index = (b*125+T)*4096 + s2*1024 + cg*512 + p*256 + c31*8 + j
//   holds V[c=cg*32+c31][key = T*64 + s2*16 + p*8 + j]

// ---------------------------------------------------------------------------
// Kernel 1: projection GEMM. 500 blocks x 192 thr, 32 distinct voxels/block.
// (R9 verbatim — proven; qkv is off the critical path.)
// ---------------------------------------------------------------------------
__global__ __launch_bounds__(192) void qkv_kernel(
    const float* __restrict__ x,
    const float* __restrict__ wq, const float* __restrict__ bq,
    const float* __restrict__ wk, const float* __restrict__ bk,
    const float* __restrict__ wv, const float* __restrict__ bv,
    unsigned short* __restrict__ qws, unsigned short* __restrict__ kws,
    unsigned short* __restrict__ vws)
{
    // st rows: 0-7 q-hi, 8-15 k, 16-79 v, 80-87 q-lo; cols = 32 voxels; stride 40
    __shared__ __align__(16) unsigned short st[88 * 40];
    const int t = threadIdx.x, lane = t & 63, ot = t >> 6;   // ot 0..2
    const int l31 = lane & 31, h = lane >> 5;
    const int blk = blockIdx.x, b = blk / 250, v0 = (blk % 250) * 32;
    const int n = v0 + l31;

    const int o = ot * 32 + l31;
    const float* wsrc;
    float scale = 1.0f;
    if (o < 8)       { wsrc = wq + o * 64; scale = LOG2E; }
    else if (o < 16) { wsrc = wk + (o - 8) * 64; }
    else             { wsrc = wv + ((o - 16) & 63) * 64; }   // o>=80: junk, never stored

    bf16x8 Ah[4], Al[4];
#pragma unroll
    for (int cc = 0; cc < 4; ++cc) {
        float4 w0 = *(const float4*)(wsrc + cc * 16 + 8 * h);
        float4 w1 = *(const float4*)(wsrc + cc * 16 + 8 * h + 4);
        float wf[8] = { w0.x, w0.y, w0.z, w0.w, w1.x, w1.y, w1.z, w1.w };
        unsigned short hh[8], ll[8];
#pragma unroll
        for (int j = 0; j < 8; ++j) {
            float wv_ = wf[j] * scale;
            __bf16 hb = (__bf16)wv_;
            hh[j] = __builtin_bit_cast(unsigned short, hb);
            ll[j] = f2bf(wv_ - (float)hb);
        }
        Ah[cc] = __builtin_bit_cast(bf16x8, *(u16x8*)hh);
        Al[cc] = __builtin_bit_cast(bf16x8, *(u16x8*)ll);
    }

    bf16x8 Bhi[4], Blo[4];
    const float* xb = x + (size_t)b * 64 * NVOX + n;
#pragma unroll
    for (int cc = 0; cc < 4; ++cc) {
        unsigned short bh[8], bl[8];
#pragma unroll
        for (int j = 0; j < 8; ++j) {
            float xf = xb[(size_t)(cc * 16 + 8 * h + j) * NVOX];
            __bf16 xh = (__bf16)xf;
            bh[j] = __builtin_bit_cast(unsigned short, xh);
            bl[j] = f2bf(xf - (float)xh);
        }
        Bhi[cc] = __builtin_bit_cast(bf16x8, *(u16x8*)bh);
        Blo[cc] = __builtin_bit_cast(bf16x8, *(u16x8*)bl);
    }

    f32x16 acc;
#pragma unroll
    for (int r = 0; r < 16; ++r) acc[r] = 0.0f;
#pragma unroll
    for (int cc = 0; cc < 4; ++cc) {
        acc = __builtin_amdgcn_mfma_f32_32x32x16_bf16(Ah[cc], Bhi[cc], acc, 0, 0, 0);
        acc = __builtin_amdgcn_mfma_f32_32x32x16_bf16(Al[cc], Bhi[cc], acc, 0, 0, 0);
        acc = __builtin_amdgcn_mfma_f32_32x32x16_bf16(Ah[cc], Blo[cc], acc, 0, 0, 0);
    }

#pragma unroll
    for (int r = 0; r < 16; ++r) {
        int oo = ot * 32 + (r & 3) + 8 * (r >> 2) + 4 * h;
        if (oo >= 80) continue;
        float bias = (oo < 8) ? bq[oo] * LOG2E : (oo < 16) ? bk[oo - 8] : bv[oo - 16];
        float v = acc[r] + bias;
        if (oo < 8) {
            __bf16 hb = (__bf16)v;
            st[oo * 40 + l31]        = __builtin_bit_cast(unsigned short, hb);
            st[(80 + oo) * 40 + l31] = f2bf(v - (float)hb);
        } else {
            st[oo * 40 + l31] = f2bf(v);
        }
    }
    __syncthreads();

    // ---- coalesced 16B stores ----
    for (int idx = t; idx < 256; idx += 192) {
        int ch = idx >> 2, q = idx & 3;
        int T = v0 >> 6;
        int off = (v0 & 63) + q * 8;
        int s2 = off >> 4, p = (off >> 3) & 1;
        int cg = ch >> 5, c31 = ch & 31;
        size_t dst = (size_t)(b * 125 + T) * 4096 + s2 * 1024 + cg * 512
                   + p * 256 + c31 * 8;
        *(uint4*)(vws + dst) = *(const uint4*)&st[(16 + ch) * 40 + q * 8];
    }
    if (t >= 128) {                      // qws: 32 vox x {hi,lo} = 64 units
        int i = t - 128, vox = i >> 1, half = i & 1;
        int rbase = half ? 80 : 0;
        unsigned short g[8];
#pragma unroll
        for (int r = 0; r < 8; ++r) g[r] = st[(rbase + r) * 40 + vox];
        *(uint4*)(qws + (size_t)(b * NVOX + v0 + vox) * 16 + half * 8) = *(uint4*)g;
    } else if (t >= 96) {                // kws: 32 vox
        int vox = t - 96;
        unsigned short g[8];
#pragma unroll
        for (int r = 0; r < 8; ++r) g[r] = st[(8 + r) * 40 + vox];
        *(uint4*)(kws + (size_t)(b * NVOX + v0 + vox) * 8) = *(uint4*)g;
    }
}

// ---------------------------------------------------------------------------
// Kernel 2: flash attention. 500 blocks x 512 thr, wave w owns tiles T = w+8S.
// R17: register-lean un-deferred pipeline so (512,4) fits WITHOUT spilling
// (R15/(512,4) spilled: 60MB scratch writes, 84us — live set was ~150 regs):
//   (a) PV un-deferred: pf transient within the iteration, no drain  (-16)
//   (b) V loads split in halves (s2=0,1 then s2=2,3): peak va 16     (-16)
//   (c) no persistent -MSTAT vector: scratch E re-init'd per QK-MFMA (-16)
//   (d) interleave: E0 -> exp0 -> E1-issue -> PV-A (covers E1 latency)
//       -> va-2nd loads -> exp1 -> PV-B
// Peak live ~104 regs -> 4 waves/SIMD real. TLP (4 waves) replaces the
// intra-wave ILP the deferral provided.
// ---------------------------------------------------------------------------
__global__ __launch_bounds__(512, 4) void attn_kernel(
    const unsigned short* __restrict__ qws, const unsigned short* __restrict__ kws,
    const unsigned short* __restrict__ vws, const float* __restrict__ x,
    const float* __restrict__ gamma, float* __restrict__ out)
{
    __shared__ float smem_f[8704];          // 32KB merge + 2KB l
    float* l_sh = smem_f + 8192;            // [8][64]

    const int blk = blockIdx.x, b = blk / QTILES, m0 = (blk % QTILES) * MT;
    const int t = threadIdx.x, lane = t & 63, w = t >> 6;
    const int l31 = lane & 31, h = lane >> 5;

    // Q B-frag (log2e pre-folded): col=query l31, h=0 hi / h=1 lo
    const bf16x8 qf = __builtin_bit_cast(bf16x8,
        *(const u16x8*)(qws + (size_t)(b * NVOX + m0 + l31) * 16 + h * 8));

    const unsigned short* ksrc = kws + (size_t)b * NVOX * 8;
    const unsigned short* vbase = vws + (size_t)b * 512000 + h * 256 + l31 * 8;

    f32x16 acc0, acc1;
#pragma unroll
    for (int r = 0; r < 16; ++r) { acc0[r] = 0.0f; acc1[r] = 0.0f; }
    float sA = 0.0f, sB = 0.0f, sC = 0.0f, sD = 0.0f;

    bf16x8 kf0c = __builtin_bit_cast(bf16x8, *(const u16x8*)(ksrc + (size_t)(w * KT + l31) * 8));
    bf16x8 kf1c = __builtin_bit_cast(bf16x8, *(const u16x8*)(ksrc + (size_t)(w * KT + 32 + l31) * 8));

#pragma unroll 1
    for (int S = 0; S < 16; ++S) {
        const int T = w + 8 * S;
        if (T < NTILES) {
            const unsigned short* vt = vbase + (size_t)T * 4096;

            // V first half (s2 = 0,1): issued at top, consumed after exp0.
            uint4 vA0 = *(const uint4*)(vt);                 // cg0, s2=0
            uint4 vB0 = *(const uint4*)(vt + 512);           // cg1, s2=0
            uint4 vA1 = *(const uint4*)(vt + 1024);          // cg0, s2=1
            uint4 vB1 = *(const uint4*)(vt + 1024 + 512);    // cg1, s2=1

            // E0 = K0·Q - MSTAT (scratch C, re-init'd: allocator rematerializes
            // the constant instead of pinning 16 regs)
            f32x16 E;
#pragma unroll
            for (int r = 0; r < 16; ++r) E[r] = -MSTAT;
            E = __builtin_amdgcn_mfma_f32_32x32x16_bf16(kf0c, qf, E, 0, 0, 0);
            // K half-0 for T+8: kf0c dead after the issue above
            if (T + 8 < NTILES) {
                kf0c = __builtin_bit_cast(bf16x8,
                    *(const u16x8*)(ksrc + (size_t)((T + 8) * KT + l31) * 8));
            }

            // exp0/pack0 -> pf0, pf1 (keys 0..31 of the tile)
            uint4 pfa, pfb;
            {
                unsigned int pk[8];
#pragma unroll
                for (int g = 0; g < 8; ++g) {
                    float pa = fexp2(E[2 * g]);
                    float pb = fexp2(E[2 * g + 1]);
                    sA += pa; sB += pb;
                    pk[g] = packbf(pa, pb);
                }
                unsigned a0, b0;
                a0 = pk[0]; b0 = pk[2]; plswap(a0, b0); pfa.x = a0; pfa.z = b0;
                a0 = pk[1]; b0 = pk[3]; plswap(a0, b0); pfa.y = a0; pfa.w = b0;
                a0 = pk[4]; b0 = pk[6]; plswap(a0, b0); pfb.x = a0; pfb.z = b0;
                a0 = pk[5]; b0 = pk[7]; plswap(a0, b0); pfb.y = a0; pfb.w = b0;
            }

            // E1 issued BEFORE PV-A: the 4 PV MFMAs below cover its latency.
            f32x16 E2;
#pragma unroll
            for (int r = 0; r < 16; ++r) E2[r] = -MSTAT;
            E2 = __builtin_amdgcn_mfma_f32_32x32x16_bf16(kf1c, qf, E2, 0, 0, 0);
            if (T + 8 < NTILES) {
                kf1c = __builtin_bit_cast(bf16x8,
                    *(const u16x8*)(ksrc + (size_t)((T + 8) * KT + 32 + l31) * 8));
            }

            // PV half A (s2 = 0,1) — consumes pfa/pfb and the first V half.
            __builtin_amdgcn_s_setprio(1);
            acc0 = __builtin_amdgcn_mfma_f32_32x32x16_bf16(
                __builtin_bit_cast(bf16x8, vA0), __builtin_bit_cast(bf16x8, pfa), acc0, 0, 0, 0);
            acc1 = __builtin_amdgcn_mfma_f32_32x32x16_bf16(
                __builtin_bit_cast(bf16x8, vB0), __builtin_bit_cast(bf16x8, pfa), acc1, 0, 0, 0);
            acc0 = __builtin_amdgcn_mfma_f32_32x32x16_bf16(
                __builtin_bit_cast(bf16x8, vA1), __builtin_bit_cast(bf16x8, pfb), acc0, 0, 0, 0);
            acc1 = __builtin_amdgcn_mfma_f32_32x32x16_bf16(
                __builtin_bit_cast(bf16x8, vB1), __builtin_bit_cast(bf16x8, pfb), acc1, 0, 0, 0);
            __builtin_amdgcn_s_setprio(0);

            // V second half (s2 = 2,3): reuses the vA/vB regs just consumed;
            // lead = exp1 chain (~200cy) covers L2 latency.
            vA0 = *(const uint4*)(vt + 2048);
            vB0 = *(const uint4*)(vt + 2048 + 512);
            vA1 = *(const uint4*)(vt + 3072);
            vB1 = *(const uint4*)(vt + 3072 + 512);

            // exp1/pack1 -> pf2, pf3 (keys 32..63)
            {
                unsigned int pk[8];
#pragma unroll
                for (int g = 0; g < 8; ++g) {
                    float pa = fexp2(E2[2 * g]);
                    float pb = fexp2(E2[2 * g + 1]);
                    sC += pa; sD += pb;
                    pk[g] = packbf(pa, pb);
                }
                unsigned a0, b0;
                a0 = pk[0]; b0 = pk[2]; plswap(a0, b0); pfa.x = a0; pfa.z = b0;
                a0 = pk[1]; b0 = pk[3]; plswap(a0, b0); pfa.y = a0; pfa.w = b0;
                a0 = pk[4]; b0 = pk[6]; plswap(a0, b0); pfb.x = a0; pfb.z = b0;
                a0 = pk[5]; b0 = pk[7]; plswap(a0, b0); pfb.y = a0; pfb.w = b0;
            }

            // PV half B (s2 = 2,3)
            __builtin_amdgcn_s_setprio(1);
            acc0 = __builtin_amdgcn_mfma_f32_32x32x16_bf16(
                __builtin_bit_cast(bf16x8, vA0), __builtin_bit_cast(bf16x8, pfa), acc0, 0, 0, 0);
            acc1 = __builtin_amdgcn_mfma_f32_32x32x16_bf16(
                __builtin_bit_cast(bf16x8, vB0), __builtin_bit_cast(bf16x8, pfa), acc1, 0, 0, 0);
            acc0 = __builtin_amdgcn_mfma_f32_32x32x16_bf16(
                __builtin_bit_cast(bf16x8, vA1), __builtin_bit_cast(bf16x8, pfb), acc0, 0, 0, 0);
            acc1 = __builtin_amdgcn_mfma_f32_32x32x16_bf16(
                __builtin_bit_cast(bf16x8, vB1), __builtin_bit_cast(bf16x8, pfb), acc1, 0, 0, 0);
            __builtin_amdgcn_s_setprio(0);
        }
    }

    // ---- tree merge (plain sums, static m) ----
    l_sh[w * 64 + lane] = (sA + sB) + (sC + sD);
    float* mw = smem_f;
    auto wr = [&](int srcw) {
#pragma unroll
        for (int r4 = 0; r4 < 4; ++r4) {
            *(float4*)&mw[((size_t)(srcw * 2 + 0) * 64 + lane) * 16 + 4 * r4] =
                make_float4(acc0[4*r4], acc0[4*r4+1], acc0[4*r4+2], acc0[4*r4+3]);
            *(float4*)&mw[((size_t)(srcw * 2 + 1) * 64 + lane) * 16 + 4 * r4] =
                make_float4(acc1[4*r4], acc1[4*r4+1], acc1[4*r4+2], acc1[4*r4+3]);
        }
    };
    auto rd = [&](int srcw) {
#pragma unroll
        for (int r4 = 0; r4 < 4; ++r4) {
            float4 a = *(const float4*)&mw[((size_t)(srcw * 2 + 0) * 64 + lane) * 16 + 4 * r4];
            float4 c = *(const float4*)&mw[((size_t)(srcw * 2 + 1) * 64 + lane) * 16 + 4 * r4];
            acc0[4*r4]   += a.x; acc0[4*r4+1] += a.y; acc0[4*r4+2] += a.z; acc0[4*r4+3] += a.w;
            acc1[4*r4]   += c.x; acc1[4*r4+1] += c.y; acc1[4*r4+2] += c.z; acc1[4*r4+3] += c.w;
        }
    };
    if (w >= 4) wr(w - 4);
    __syncthreads();
    if (w < 4) rd(w);
    __syncthreads();
    if (w >= 2 && w < 4) wr(w - 2);
    __syncthreads();
    if (w < 2) rd(w);
    __syncthreads();
    if (w == 1) wr(0);
    __syncthreads();
    if (w == 0) {
        rd(0);
        float l_tot = 0.0f;
#pragma unroll
        for (int ww = 0; ww < 8; ++ww)
            l_tot += l_sh[ww * 64 + l31] + l_sh[ww * 64 + 32 + l31];
        const float inv = 1.0f / l_tot;
        const float g = gamma[0];
#pragma unroll
        for (int r = 0; r < 16; ++r) {
            int c = (r & 3) + 8 * (r >> 2) + 4 * h;
            size_t i0 = ((size_t)b * 64 + c) * NVOX + m0 + l31;
            size_t i1 = ((size_t)b * 64 + c + 32) * NVOX + m0 + l31;
            out[i0] = g * (acc0[r] * inv) + x[i0];
            out[i1] = g * (acc1[r] * inv) + x[i1];
        }
    }
}

// ---------------------------------------------------------------------------
extern "C" void kernel_launch(void* const* d_in, const int* in_sizes, int n_in,
                              void* d_out, int out_size, void* d_ws, size_t ws_size,
                              hipStream_t stream) {
    const float* x     = (const float*)d_in[0];
    const float* wq    = (const float*)d_in[1];
    const float* bq    = (const float*)d_in[2];
    const float* wk    = (const float*)d_in[3];
    const float* bk    = (const float*)d_in[4];
    const float* wv    = (const float*)d_in[5];
    const float* bv    = (const float*)d_in[6];
    const float* gamma = (const float*)d_in[7];
    float* out = (float*)d_out;

    unsigned short* qws = (unsigned short*)d_ws;            // [16000][16] hi|lo (log2e-scaled)
    unsigned short* kws = qws + (size_t)BATCH * NVOX * 16;  // [16000][8]
    unsigned short* vws = kws + (size_t)BATCH * NVOX * 8;   // [2][125][4][2][2][32][8] frag-linear

    qkv_kernel<<<500, 192, 0, stream>>>(x, wq, bq, wk, bk, wv, bv, qws, kws, vws);
    attn_kernel<<<BATCH * QTILES, 512, 0, stream>>>(qws, kws, vws, x, gamma, out);
}